// Round 4
// baseline (1235.095 us; speedup 1.0000x reference)
//
#include <hip/hip_runtime.h>
#include <hip/hip_bf16.h>

// Problem constants (fixed by reference)
#define V_NODES 50000
#define N_EDGES 500000
#define H_DIM 128
#define NCLUST 10
#define BN_EPS 1e-5f
#define NB_SCAN ((V_NODES + 255) / 256)   // 196

// ---------------------------------------------------------------------------
// x[v] = emb[signal[v]]   (float4-vectorized gather)
// ---------------------------------------------------------------------------
__global__ __launch_bounds__(256) void embed_kernel(const int* __restrict__ signal,
                                                    const float* __restrict__ emb,
                                                    float* __restrict__ x) {
    int idx = blockIdx.x * 256 + threadIdx.x;       // over V*32 float4s
    if (idx >= V_NODES * 32) return;
    int v = idx >> 5;
    int q = idx & 31;
    int s = signal[v];
    ((float4*)x)[idx] = ((const float4*)emb)[s * 32 + q];
}

// ---------------------------------------------------------------------------
// CSR build (by destination node). deg must be zeroed beforehand.
// ---------------------------------------------------------------------------
__global__ __launch_bounds__(256) void hist_kernel(const int* __restrict__ end_idx,
                                                   int* __restrict__ deg) {
    int e = blockIdx.x * 256 + threadIdx.x;
    if (e >= N_EDGES) return;
    atomicAdd(&deg[end_idx[e]], 1);
}

__global__ __launch_bounds__(256) void reduce_block_kernel(const int* __restrict__ deg,
                                                           int* __restrict__ blockSums) {
    __shared__ int sh[256];
    int t = threadIdx.x;
    int i = blockIdx.x * 256 + t;
    sh[t] = (i < V_NODES) ? deg[i] : 0;
    __syncthreads();
    for (int s = 128; s > 0; s >>= 1) {
        if (t < s) sh[t] += sh[t + s];
        __syncthreads();
    }
    if (t == 0) blockSums[blockIdx.x] = sh[0];
}

__global__ void scan_sums_kernel(const int* __restrict__ blockSums,
                                 int* __restrict__ blockOffs) {
    if (threadIdx.x == 0) {
        int run = 0;
        for (int i = 0; i < NB_SCAN; ++i) { blockOffs[i] = run; run += blockSums[i]; }
    }
}

__global__ __launch_bounds__(256) void scan_block_kernel(const int* __restrict__ deg,
                                                         const int* __restrict__ blockOffs,
                                                         int* __restrict__ offsets) {
    __shared__ int sh[256];
    int t = threadIdx.x;
    int i = blockIdx.x * 256 + t;
    int v = (i < V_NODES) ? deg[i] : 0;
    sh[t] = v;
    __syncthreads();
    int run = v;
    for (int ofs = 1; ofs < 256; ofs <<= 1) {
        int add = (t >= ofs) ? sh[t - ofs] : 0;
        __syncthreads();
        run += add;
        sh[t] = run;
        __syncthreads();
    }
    if (i < V_NODES) offsets[i] = run - v + blockOffs[blockIdx.x];
}

// cursor starts as a copy of offsets; edge_src[p] = start node, grouped by dst
__global__ __launch_bounds__(256) void scatter_kernel(const int* __restrict__ start_idx,
                                                      const int* __restrict__ end_idx,
                                                      int* __restrict__ cursor,
                                                      int* __restrict__ edge_src) {
    int e = blockIdx.x * 256 + threadIdx.x;
    if (e >= N_EDGES) return;
    int d = end_idx[e];
    int p = atomicAdd(&cursor[d], 1);
    edge_src[p] = start_idx[e];
}

// ---------------------------------------------------------------------------
// Multi-weight GEMM: out_w = X @ W_w^T (+ bias_w), W_w is [128,128] row-major.
// Block: 256 threads, 64-row tile. X tile staged once in LDS, reused for all
// weights. W chunks staged transposed (wsh[kk][j]) so B reads are b128.
// Thread tile: 8 rows x 4 cols (B fragment reused across 8 rows -> LDS
// traffic 0.27 B/FLOP, under the 0.44 B/FLOP LDS-vs-VALU balance point).
// A fragments loaded as float4 over k (lane-broadcast, cheap).
// ---------------------------------------------------------------------------
struct GemmArgs {
    const float* W[5];
    const float* bias[5];
    float*       out[5];
    int          nw;
};

__global__ __launch_bounds__(256) void gemm_multi(const float* __restrict__ X,
                                                  GemmArgs args) {
    __shared__ float xs[64][132];     // +4 pad
    __shared__ float wsh[16][132];    // transposed k-chunk: wsh[kk][j]
    const int t = threadIdx.x;
    const int row0 = blockIdx.x * 64;

    // stage X tile: 64 rows x 128 cols (coalesced float4 global reads)
#pragma unroll
    for (int it = 0; it < 8; ++it) {
        int idx = t + it * 256;       // float4 index 0..2047
        int r = idx >> 5;
        int q = idx & 31;
        float4 v = make_float4(0.f, 0.f, 0.f, 0.f);
        if (row0 + r < V_NODES) v = ((const float4*)X)[(row0 + r) * 32 + q];
        xs[r][q * 4 + 0] = v.x; xs[r][q * 4 + 1] = v.y;
        xs[r][q * 4 + 2] = v.z; xs[r][q * 4 + 3] = v.w;
    }

    const int cg = t & 31;            // cols cg*4 .. cg*4+3
    const int rg = t >> 5;            // rows rg*8 .. rg*8+7

    for (int w = 0; w < args.nw; ++w) {
        const float* __restrict__ W = args.W[w];
        float acc[8][4];
#pragma unroll
        for (int i = 0; i < 8; ++i)
#pragma unroll
            for (int j = 0; j < 4; ++j) acc[i][j] = 0.f;

        for (int k0 = 0; k0 < 128; k0 += 16) {
            __syncthreads();          // protect wsh (and first-iter xs)
            // stage W chunk transposed: wsh[kk][j] = W[j][k0+kk]
#pragma unroll
            for (int it = 0; it < 2; ++it) {
                int idx = t + it * 256;          // float4 index 0..511
                int j = idx >> 2;                // 0..127
                int kq = idx & 3;
                float4 v = ((const float4*)W)[j * 32 + (k0 >> 2) + kq];
                wsh[kq * 4 + 0][j] = v.x; wsh[kq * 4 + 1][j] = v.y;
                wsh[kq * 4 + 2][j] = v.z; wsh[kq * 4 + 3][j] = v.w;
            }
            __syncthreads();
#pragma unroll
            for (int u = 0; u < 4; ++u) {        // 4 kk per a4-load
                float4 a4[8];
#pragma unroll
                for (int i = 0; i < 8; ++i)
                    a4[i] = *(const float4*)&xs[rg * 8 + i][k0 + u * 4];
#pragma unroll
                for (int c2 = 0; c2 < 4; ++c2) { // kk = u*4 + c2
                    float4 b4 = *(const float4*)&wsh[u * 4 + c2][cg * 4];
                    float b[4] = {b4.x, b4.y, b4.z, b4.w};
#pragma unroll
                    for (int i = 0; i < 8; ++i) {
                        float av = ((const float*)&a4[i])[c2];
#pragma unroll
                        for (int j = 0; j < 4; ++j) acc[i][j] += av * b[j];
                    }
                }
            }
        }

        // epilogue: bias + store (one float4 per row per thread, coalesced)
        const float* bias = args.bias[w];
        float bb[4];
#pragma unroll
        for (int j = 0; j < 4; ++j) bb[j] = bias ? bias[cg * 4 + j] : 0.f;
        float* O = args.out[w];
#pragma unroll
        for (int i = 0; i < 8; ++i) {
            int r = row0 + rg * 8 + i;
            if (r < V_NODES) {
                float4 o = make_float4(acc[i][0] + bb[0], acc[i][1] + bb[1],
                                       acc[i][2] + bb[2], acc[i][3] + bb[3]);
                ((float4*)O)[r * 32 + cg] = o;
            }
        }
    }
}

// ---------------------------------------------------------------------------
// Gather-style aggregation (no atomics).
// agg[d] is prefilled with Uix[d] + bu by the GEMM stage. For each node d:
//   acc = agg[d]; for each in-edge (s -> d):
//     acc += sigmoid(Vix[d] + Vjx[s] + bv) * Ujx[s]
// Block: 256 threads = 8 nodes x 32 lanes (float4 per lane).
// ---------------------------------------------------------------------------
__global__ __launch_bounds__(256) void agg_kernel(const float* __restrict__ Vix,
                                                  const float* __restrict__ Vjx,
                                                  const float* __restrict__ Ujx,
                                                  const float* __restrict__ bv,
                                                  const int* __restrict__ offsets,
                                                  const int* __restrict__ deg,
                                                  const int* __restrict__ edge_src,
                                                  float* __restrict__ agg) {
    int t = threadIdx.x;
    int node = blockIdx.x * 8 + (t >> 5);
    int q = t & 31;
    if (node >= V_NODES) return;

    float4 vi  = ((const float4*)Vix)[node * 32 + q];
    float4 bvv = ((const float4*)bv)[q];
    float4 acc = ((const float4*)agg)[node * 32 + q];   // Uix + bu prefill

    int off = offsets[node];
    int dg  = deg[node];
#pragma unroll 2
    for (int i = 0; i < dg; ++i) {
        int s = edge_src[off + i];                      // broadcast across 32 lanes
        float4 vj = ((const float4*)Vjx)[s * 32 + q];
        float4 uj = ((const float4*)Ujx)[s * 32 + q];
        float g0 = 1.f / (1.f + __expf(-(vi.x + vj.x + bvv.x)));
        float g1 = 1.f / (1.f + __expf(-(vi.y + vj.y + bvv.y)));
        float g2 = 1.f / (1.f + __expf(-(vi.z + vj.z + bvv.z)));
        float g3 = 1.f / (1.f + __expf(-(vi.w + vj.w + bvv.w)));
        acc.x += g0 * uj.x;
        acc.y += g1 * uj.y;
        acc.z += g2 * uj.z;
        acc.w += g3 * uj.w;
    }
    ((float4*)agg)[node * 32 + q] = acc;
}

// ---------------------------------------------------------------------------
// Per-column sum / sum-of-squares over V rows -> stats[0..127]=sum,
// stats[128..255]=sumsq. stats must be zeroed beforehand.
// ---------------------------------------------------------------------------
__global__ __launch_bounds__(256) void bn_stats_kernel(const float* __restrict__ h,
                                                       float* __restrict__ stats) {
    __shared__ float s1[256], s2[256];
    int t = threadIdx.x;
    int j = t & 127;
    int half = t >> 7;
    float sum = 0.f, ss = 0.f;
    for (int r = blockIdx.x * 2 + half; r < V_NODES; r += gridDim.x * 2) {
        float v = h[r * 128 + j];
        sum += v; ss += v * v;
    }
    s1[t] = sum; s2[t] = ss;
    __syncthreads();
    if (t < 128) {
        sum = s1[t] + s1[t + 128];
        ss = s2[t] + s2[t + 128];
        atomicAdd(&stats[j], sum);
        atomicAdd(&stats[128 + j], ss);
    }
}

// ---------------------------------------------------------------------------
// x2 = relu(g*(h-mean)*rsqrt(var+eps)+b)
// ---------------------------------------------------------------------------
__global__ __launch_bounds__(256) void norm_relu_kernel(const float* __restrict__ h,
                                                        const float* __restrict__ stats,
                                                        const float* __restrict__ g,
                                                        const float* __restrict__ b,
                                                        float* __restrict__ out) {
    int idx = blockIdx.x * 256 + threadIdx.x;       // over V*32
    if (idx >= V_NODES * 32) return;
    int q = idx & 31;
    float4 hv = ((const float4*)h)[idx];
    float hvv[4] = {hv.x, hv.y, hv.z, hv.w};
    const float invV = 1.f / (float)V_NODES;
    float o[4];
#pragma unroll
    for (int c = 0; c < 4; ++c) {
        int j = q * 4 + c;
        float m = stats[j] * invV;
        float var = stats[128 + j] * invV - m * m;
        float sc = g[j] * rsqrtf(var + BN_EPS);
        float val = (hvv[c] - m) * sc + b[j];
        o[c] = fmaxf(val, 0.f);
    }
    ((float4*)out)[idx] = make_float4(o[0], o[1], o[2], o[3]);
}

// x3 = relu(bn(h) + rx)
__global__ __launch_bounds__(256) void norm_res_relu_kernel(const float* __restrict__ h,
                                                            const float* __restrict__ stats,
                                                            const float* __restrict__ g,
                                                            const float* __restrict__ b,
                                                            const float* __restrict__ rx,
                                                            float* __restrict__ out) {
    int idx = blockIdx.x * 256 + threadIdx.x;
    if (idx >= V_NODES * 32) return;
    int q = idx & 31;
    float4 hv = ((const float4*)h)[idx];
    float4 rv = ((const float4*)rx)[idx];
    float hvv[4] = {hv.x, hv.y, hv.z, hv.w};
    float rvv[4] = {rv.x, rv.y, rv.z, rv.w};
    const float invV = 1.f / (float)V_NODES;
    float o[4];
#pragma unroll
    for (int c = 0; c < 4; ++c) {
        int j = q * 4 + c;
        float m = stats[j] * invV;
        float var = stats[128 + j] * invV - m * m;
        float sc = g[j] * rsqrtf(var + BN_EPS);
        float val = (hvv[c] - m) * sc + b[j] + rvv[c];
        o[c] = fmaxf(val, 0.f);
    }
    ((float4*)out)[idx] = make_float4(o[0], o[1], o[2], o[3]);
}

// ---------------------------------------------------------------------------
// out[v,k] = sum_h x[v,h]*fc_w[k,h] + fc_b[k]    (k=0..9)
// ---------------------------------------------------------------------------
__global__ __launch_bounds__(256) void fc_kernel(const float* __restrict__ X,
                                                 const float* __restrict__ fw,
                                                 const float* __restrict__ fb,
                                                 float* __restrict__ out) {
    __shared__ float fwsh[NCLUST][132];
    __shared__ float fbsh[NCLUST];
    int t = threadIdx.x;
    for (int i = t; i < NCLUST * 128; i += 256) fwsh[i >> 7][i & 127] = fw[i];
    if (t < NCLUST) fbsh[t] = fb[t];
    __syncthreads();
    int rl = t >> 5;
    int q = t & 31;
    int r = blockIdx.x * 8 + rl;
    float4 xv = make_float4(0.f, 0.f, 0.f, 0.f);
    if (r < V_NODES) xv = ((const float4*)X)[r * 32 + q];
    float p[NCLUST];
#pragma unroll
    for (int k = 0; k < NCLUST; ++k) {
        float4 wv = *(const float4*)&fwsh[k][q * 4];
        p[k] = xv.x * wv.x + xv.y * wv.y + xv.z * wv.z + xv.w * wv.w;
    }
#pragma unroll
    for (int off = 16; off > 0; off >>= 1)
#pragma unroll
        for (int k = 0; k < NCLUST; ++k) p[k] += __shfl_down(p[k], off, 32);
    if (q == 0 && r < V_NODES) {
#pragma unroll
        for (int k = 0; k < NCLUST; ++k) out[r * NCLUST + k] = p[k] + fbsh[k];
    }
}

// ---------------------------------------------------------------------------
extern "C" void kernel_launch(void* const* d_in, const int* in_sizes, int n_in,
                              void* d_out, int out_size, void* d_ws, size_t ws_size,
                              hipStream_t stream) {
    (void)in_sizes; (void)n_in; (void)out_size; (void)ws_size;
    const int*   signal    = (const int*)d_in[0];
    const int*   start_idx = (const int*)d_in[1];
    const int*   end_idx   = (const int*)d_in[2];
    const float* emb       = (const float*)d_in[3];
    const float* Ui1 = (const float*)d_in[4];
    const float* Uj1 = (const float*)d_in[5];
    const float* Vi1 = (const float*)d_in[6];
    const float* Vj1 = (const float*)d_in[7];
    const float* Ui2 = (const float*)d_in[8];
    const float* Uj2 = (const float*)d_in[9];
    const float* Vi2 = (const float*)d_in[10];
    const float* Vj2 = (const float*)d_in[11];
    const float* Rw  = (const float*)d_in[12];
    const float* bu1 = (const float*)d_in[13];
    const float* bv1 = (const float*)d_in[14];
    const float* bu2 = (const float*)d_in[15];
    const float* bv2 = (const float*)d_in[16];
    const float* bn1_g = (const float*)d_in[17];
    const float* bn2_g = (const float*)d_in[18];
    const float* bn1_b = (const float*)d_in[19];
    const float* bn2_b = (const float*)d_in[20];
    const float* fc_w  = (const float*)d_in[21];
    const float* fc_b  = (const float*)d_in[22];
    float* out = (float*)d_out;

    // workspace layout: 6 f32 node buffers (25.6 MB each) + stats + CSR arrays
    const size_t VH = (size_t)V_NODES * H_DIM;
    float* ws  = (float*)d_ws;
    float* X   = ws + 0 * VH;
    float* VI  = ws + 1 * VH;
    float* VJ  = ws + 2 * VH;
    float* UJ  = ws + 3 * VH;
    float* AGG = ws + 4 * VH;   // Uix + bu, then += gathered messages
    float* RX  = ws + 5 * VH;
    float* stats = ws + 6 * VH;                 // 4 x 256 floats
    int* ip        = (int*)(stats + 4 * 256);
    int* deg       = ip;                        // V
    int* offsets   = ip + V_NODES;              // V
    int* cursor    = ip + 2 * V_NODES;          // V
    int* blockSums = ip + 3 * V_NODES;          // NB_SCAN
    int* blockOffs = blockSums + NB_SCAN;       // NB_SCAN
    int* edge_src  = blockOffs + NB_SCAN;       // N_EDGES

    hipMemsetAsync(stats, 0, 4 * 256 * sizeof(float), stream);
    hipMemsetAsync(deg, 0, V_NODES * sizeof(int), stream);

    const int vec_grid  = (V_NODES * 32 + 255) / 256;   // 6250
    const int gemm_grid = (V_NODES + 63) / 64;          // 782
    const int edge_grid = (N_EDGES + 255) / 256;        // 1954
    const int node_grid = (V_NODES + 7) / 8;            // 6250

    // ---- CSR build (end_idx is the same for both cells) ----
    hist_kernel<<<edge_grid, 256, 0, stream>>>(end_idx, deg);
    reduce_block_kernel<<<NB_SCAN, 256, 0, stream>>>(deg, blockSums);
    scan_sums_kernel<<<1, 64, 0, stream>>>(blockSums, blockOffs);
    scan_block_kernel<<<NB_SCAN, 256, 0, stream>>>(deg, blockOffs, offsets);
    hipMemcpyAsync(cursor, offsets, V_NODES * sizeof(int),
                   hipMemcpyDeviceToDevice, stream);
    scatter_kernel<<<edge_grid, 256, 0, stream>>>(start_idx, end_idx, cursor, edge_src);

    embed_kernel<<<vec_grid, 256, 0, stream>>>(signal, emb, X);

    for (int c = 0; c < 2; ++c) {
        const int wo = c * H_DIM * H_DIM;
        const int bo = c * H_DIM;

        // ---- half-cell 1: 4 GEMMs + residual GEMM (R uses cell input x) ----
        GemmArgs g1;
        g1.W[0] = Vi1 + wo; g1.bias[0] = nullptr;  g1.out[0] = VI;
        g1.W[1] = Vj1 + wo; g1.bias[1] = nullptr;  g1.out[1] = VJ;
        g1.W[2] = Uj1 + wo; g1.bias[2] = nullptr;  g1.out[2] = UJ;
        g1.W[3] = Ui1 + wo; g1.bias[3] = bu1 + bo; g1.out[3] = AGG;
        g1.W[4] = Rw  + wo; g1.bias[4] = nullptr;  g1.out[4] = RX;
        g1.nw = 5;
        gemm_multi<<<gemm_grid, 256, 0, stream>>>(X, g1);
        agg_kernel<<<node_grid, 256, 0, stream>>>(VI, VJ, UJ, bv1 + bo,
                                                  offsets, deg, edge_src, AGG);
        bn_stats_kernel<<<1024, 256, 0, stream>>>(AGG, stats + c * 512);
        norm_relu_kernel<<<vec_grid, 256, 0, stream>>>(AGG, stats + c * 512,
                                                       bn1_g + bo, bn1_b + bo, X);

        // ---- half-cell 2 ----
        GemmArgs g2;
        g2.W[0] = Vi2 + wo; g2.bias[0] = nullptr;  g2.out[0] = VI;
        g2.W[1] = Vj2 + wo; g2.bias[1] = nullptr;  g2.out[1] = VJ;
        g2.W[2] = Uj2 + wo; g2.bias[2] = nullptr;  g2.out[2] = UJ;
        g2.W[3] = Ui2 + wo; g2.bias[3] = bu2 + bo; g2.out[3] = AGG;
        g2.nw = 4;
        gemm_multi<<<gemm_grid, 256, 0, stream>>>(X, g2);
        agg_kernel<<<node_grid, 256, 0, stream>>>(VI, VJ, UJ, bv2 + bo,
                                                  offsets, deg, edge_src, AGG);
        bn_stats_kernel<<<1024, 256, 0, stream>>>(AGG, stats + c * 512 + 256);
        norm_res_relu_kernel<<<vec_grid, 256, 0, stream>>>(AGG, stats + c * 512 + 256,
                                                           bn2_g + bo, bn2_b + bo,
                                                           RX, X);
    }

    fc_kernel<<<(V_NODES + 7) / 8, 256, 0, stream>>>(X, fc_w, fc_b, out);
}